// Round 7
// baseline (110.156 us; speedup 1.0000x reference)
//
#include <hip/hip_runtime.h>
#include <cstdint>
#include <cstddef>

#define HD 128
#define KD 256
#define NBMAX 512

typedef __attribute__((ext_vector_type(8))) short bf16x8;
typedef __attribute__((ext_vector_type(4))) float f32x4;
typedef __attribute__((ext_vector_type(4))) unsigned int u32x4;
typedef __attribute__((ext_vector_type(2))) _Float16 h16x2;
typedef __attribute__((ext_vector_type(4))) _Float16 h16x4;

typedef const __attribute__((address_space(1))) void gv_t;
typedef __attribute__((address_space(3))) void lv_t;

__device__ __forceinline__ void gload16(const void* g, void* l) {
    __builtin_amdgcn_global_load_lds((gv_t*)g, (lv_t*)l, 16, 0, 0);
}

__device__ __forceinline__ unsigned short f2bf(float x) {   // RNE f32->bf16
    unsigned u = __float_as_uint(x);
    u = (u + 0x7fffu + ((u >> 16) & 1u)) >> 16;
    return (unsigned short)u;
}

// ================= per-node precompute (U' = zW1a+b1, V = zW1b) ============

// pack B: Bw[k][c] (128x256): c<128 -> w1[k][c], c>=128 -> w1[128+k][c-128]
__global__ void pack_B_kernel(const float* __restrict__ w1,
                              unsigned short* __restrict__ Bp) {
    const int tid = blockIdx.x * 256 + threadIdx.x;   // 0..4095
    const int lane = tid & 63, nf = (tid >> 6) & 15, kt = tid >> 10;
    const int col = nf * 16 + (lane & 15);
    const int k0 = kt * 32 + (lane >> 4) * 8;
    #pragma unroll
    for (int j = 0; j < 8; ++j) {
        const int k = k0 + j;
        const float v = (col < HD) ? w1[(size_t)k * HD + col]
                                   : w1[(size_t)(HD + k) * HD + (col - HD)];
        Bp[(size_t)tid * 8 + j] = f2bf(v);
    }
}

// UV[n][c] f16. Swapped-operand MFMA: D^T so each lane owns one node and
// 4 consecutive cols per fragment -> 8-B stores (32/thread vs 128 scalar).
__global__ __launch_bounds__(256, 2) void uv_gemm_kernel(
    const float* __restrict__ z, const unsigned short* __restrict__ Bp,
    const float* __restrict__ b1, _Float16* __restrict__ UV, const int NN)
{
    __shared__ __attribute__((aligned(16))) unsigned short sA[128 * HD];
    char* sAb = (char*)sA;
    const int t = threadIdx.x, wave = t >> 6, l = t & 63;
    const int n0 = blockIdx.x * 128;
    {
        const int r = t >> 1, kh = t & 1;
        int n = n0 + r; if (n >= NN) n = NN - 1;
        const float* zr = z + (size_t)n * HD + kh * 64;
        #pragma unroll
        for (int q = 0; q < 16; ++q) {
            const float4 v = *(const float4*)(zr + q * 4);
            ushort4 o;
            o.x = f2bf(v.x); o.y = f2bf(v.y); o.z = f2bf(v.z); o.w = f2bf(v.w);
            const int byte = r * 256 + (kh * 64 + q * 4) * 2;
            *(ushort4*)(sAb + (byte ^ ((r & 15) << 4))) = o;
        }
    }
    __syncthreads();

    const int waveM = wave >> 1, waveN = wave & 1;
    f32x4 acc[4][8];
    #pragma unroll
    for (int nf = 0; nf < 8; ++nf) {
        // col c = waveN*128 + nf*16 + (l>>4)*4 + j ; bias only on c<128 half
        float4 bv = make_float4(0.f, 0.f, 0.f, 0.f);
        if (waveN == 0) bv = *(const float4*)(b1 + nf * 16 + (l >> 4) * 4);
        #pragma unroll
        for (int mf = 0; mf < 4; ++mf) {
            acc[mf][nf][0] = bv.x; acc[mf][nf][1] = bv.y;
            acc[mf][nf][2] = bv.z; acc[mf][nf][3] = bv.w;
        }
    }
    #pragma unroll
    for (int kt = 0; kt < 4; ++kt) {
        bf16x8 bfr[8], af[4];
        #pragma unroll
        for (int nf = 0; nf < 8; ++nf)
            bfr[nf] = *(const bf16x8*)(Bp + (size_t)((kt * 16 + waveN * 8 + nf) * 64 + l) * 8);
        #pragma unroll
        for (int mf = 0; mf < 4; ++mf) {
            const int rr = waveM * 64 + mf * 16 + (l & 15);
            const int byte = rr * 256 + kt * 64 + (l >> 4) * 16;
            af[mf] = *(const bf16x8*)(sAb + (byte ^ ((rr & 15) << 4)));
        }
        #pragma unroll
        for (int mf = 0; mf < 4; ++mf)
            #pragma unroll
            for (int nf = 0; nf < 8; ++nf)
                acc[mf][nf] = __builtin_amdgcn_mfma_f32_16x16x32_bf16(
                    bfr[nf], af[mf], acc[mf][nf], 0, 0, 0);   // swapped: D^T
    }
    // store: lane node = n0 + waveM*64 + mf*16 + (l&15); cols c0..c0+3
    #pragma unroll
    for (int mf = 0; mf < 4; ++mf) {
        const int n2 = n0 + waveM * 64 + mf * 16 + (l & 15);
        if (n2 < NN) {
            #pragma unroll
            for (int nf = 0; nf < 8; ++nf) {
                const int c0 = waveN * 128 + nf * 16 + (l >> 4) * 4;
                h16x4 o = (h16x4){(_Float16)acc[mf][nf][0], (_Float16)acc[mf][nf][1],
                                  (_Float16)acc[mf][nf][2], (_Float16)acc[mf][nf][3]};
                *(h16x4*)(UV + (size_t)n2 * KD + c0) = o;
            }
        }
    }
}

// ===================== src-bucket counting sort ==========================

__global__ void hist_kernel(const int* __restrict__ eli, const int E,
                            const int nb, int* __restrict__ hist) {
    __shared__ int lh[NBMAX];
    const int t = threadIdx.x;
    for (int b = t; b < nb; b += 256) lh[b] = 0;
    __syncthreads();
    const int per = (E + gridDim.x - 1) / gridDim.x;
    const int e0 = blockIdx.x * per;
    int e1 = e0 + per; if (e1 > E) e1 = E;
    for (int e = e0 + t; e < e1; e += 256)
        atomicAdd(&lh[eli[e] >> 8], 1);
    __syncthreads();
    for (int b = t; b < nb; b += 256)
        if (lh[b]) atomicAdd(&hist[b], lh[b]);
}

__global__ void scan_kernel(const int* __restrict__ hist, const int nb,
                            int* __restrict__ start, int* __restrict__ cursor) {
    __shared__ int sc[NBMAX];
    const int t = threadIdx.x;            // launched with NBMAX threads
    const int own = (t < nb) ? hist[t] : 0;
    sc[t] = own;
    __syncthreads();
    for (int off = 1; off < NBMAX; off <<= 1) {
        const int v = (t >= off) ? sc[t - off] : 0;
        __syncthreads();
        sc[t] += v;
        __syncthreads();
    }
    if (t < nb) {
        const int ex = sc[t] - own;       // exclusive
        start[t] = ex; cursor[t] = ex;
    }
    if (t == nb - 1) start[nb] = sc[t];
}

__global__ void scatter_kernel(const int* __restrict__ eli, const int E,
                               const int nb, int* __restrict__ cursor,
                               int* __restrict__ sorted) {
    __shared__ int lh[NBMAX];
    __shared__ int lb[NBMAX];
    const int t = threadIdx.x;
    for (int b = t; b < nb; b += 256) lh[b] = 0;
    __syncthreads();
    const int per = (E + gridDim.x - 1) / gridDim.x;
    const int e0 = blockIdx.x * per;
    int e1 = e0 + per; if (e1 > E) e1 = E;
    for (int e = e0 + t; e < e1; e += 256)
        atomicAdd(&lh[eli[e] >> 8], 1);
    __syncthreads();
    for (int b = t; b < nb; b += 256) {
        const int c = lh[b];
        lb[b] = c ? atomicAdd(&cursor[b], c) : 0;
        lh[b] = 0;
    }
    __syncthreads();
    for (int e = e0 + t; e < e1; e += 256) {
        const int s = eli[e];
        const int r = atomicAdd(&lh[s >> 8], 1);
        int* p = sorted + (size_t)(lb[s >> 8] + r) * 3;
        p[0] = s; p[1] = eli[E + e]; p[2] = e;
    }
}

// ============== XCD-pinned sorted edge pass (16 lanes/edge) ===============

__global__ __launch_bounds__(256, 8) void edge_sorted_kernel(
    const _Float16* __restrict__ UV, const int* __restrict__ sorted,
    const int* __restrict__ start, const int NB,
    const float* __restrict__ w2, const float* __restrict__ b2,
    float* __restrict__ out)
{
    const int t = threadIdx.x, cl = t & 15, g = t >> 4;
    const int xcd = blockIdx.x & 7, rank = blockIdx.x >> 3;
    const int nbx = gridDim.x >> 3;
    const int bpx = (NB + 7) >> 3;
    const int blo = xcd * bpx;
    if (blo >= NB) return;
    int bhi = blo + bpx; if (bhi > NB) bhi = NB;
    const int elo = start[blo], ehi = start[bhi];

    h16x2 w2h[4];
    {
        const float4 wlo = *(const float4*)(w2 + cl * 8);
        const float4 whi = *(const float4*)(w2 + cl * 8 + 4);
        w2h[0] = (h16x2){(_Float16)wlo.x, (_Float16)wlo.y};
        w2h[1] = (h16x2){(_Float16)wlo.z, (_Float16)wlo.w};
        w2h[2] = (h16x2){(_Float16)whi.x, (_Float16)whi.y};
        w2h[3] = (h16x2){(_Float16)whi.z, (_Float16)whi.w};
    }
    const float bb2 = b2[0];
    const h16x2 zero2 = (h16x2){(_Float16)0.f, (_Float16)0.f};

    const int stride = nbx * 16;
    int i = elo + rank * 16 + g;
    if (i >= ehi) return;
    const int* tp = sorted + (size_t)i * 3;
    int e = tp[2];
    u32x4 u = *(const u32x4*)(UV + (size_t)tp[0] * KD + cl * 8);
    u32x4 v = *(const u32x4*)(UV + (size_t)tp[1] * KD + HD + cl * 8);

    for (;;) {
        const int i2 = i + stride;
        int e2 = 0; u32x4 un, vn;
        if (i2 < ehi) {
            const int* tq = sorted + (size_t)i2 * 3;
            e2 = tq[2];
            un = *(const u32x4*)(UV + (size_t)tq[0] * KD + cl * 8);
            vn = *(const u32x4*)(UV + (size_t)tq[1] * KD + HD + cl * 8);
        }
        h16x2 acc2 = zero2;
        #pragma unroll
        for (int m = 0; m < 4; ++m) {
            union { unsigned int ui; h16x2 h2; } cu, cv;
            cu.ui = u[m]; cv.ui = v[m];
            const h16x2 h = __builtin_elementwise_max(cu.h2 + cv.h2, zero2);
            acc2 = acc2 + h * w2h[m];
        }
        float acc = (float)acc2[0] + (float)acc2[1];
        #pragma unroll
        for (int msk = 1; msk <= 8; msk <<= 1) acc += __shfl_xor(acc, msk);
        if (cl == 0) out[e] = 1.f / (1.f + __expf(-(acc + bb2)));
        if (i2 >= ehi) break;
        i = i2; e = e2; u = un; v = vn;
    }
}

// ============== mid-tier fallback: unsorted edge pass (round 6) ===========

__global__ __launch_bounds__(256, 8) void edge_uv_f16_kernel(
    const _Float16* __restrict__ UV, const int* __restrict__ eli,
    const int E, const float* __restrict__ w2, const float* __restrict__ b2,
    float* __restrict__ out)
{
    const int t = threadIdx.x;
    const int cl = t & 15;
    const int gid = (blockIdx.x * 256 + t) >> 4;
    const int ng = (gridDim.x * 256) >> 4;

    h16x2 w2h[4];
    {
        const float4 wlo = *(const float4*)(w2 + cl * 8);
        const float4 whi = *(const float4*)(w2 + cl * 8 + 4);
        w2h[0] = (h16x2){(_Float16)wlo.x, (_Float16)wlo.y};
        w2h[1] = (h16x2){(_Float16)wlo.z, (_Float16)wlo.w};
        w2h[2] = (h16x2){(_Float16)whi.x, (_Float16)whi.y};
        w2h[3] = (h16x2){(_Float16)whi.z, (_Float16)whi.w};
    }
    const float bb2 = b2[0];
    const h16x2 zero2 = (h16x2){(_Float16)0.f, (_Float16)0.f};

    int e = gid;
    if (e >= E) return;
    int s = eli[e], d = eli[E + e];
    u32x4 u = *(const u32x4*)(UV + (size_t)s * KD + cl * 8);
    u32x4 v = *(const u32x4*)(UV + (size_t)d * KD + HD + cl * 8);
    int en = e + ng;
    int enc = (en < E) ? en : (E - 1);
    int sn = eli[enc], dn = eli[E + enc];

    for (;;) {
        const int e2 = en + ng;
        const int e2c = (e2 < E) ? e2 : (E - 1);
        const int s2 = eli[e2c], d2 = eli[E + e2c];
        const u32x4 un = *(const u32x4*)(UV + (size_t)sn * KD + cl * 8);
        const u32x4 vn = *(const u32x4*)(UV + (size_t)dn * KD + HD + cl * 8);

        h16x2 acc2 = zero2;
        #pragma unroll
        for (int m = 0; m < 4; ++m) {
            union { unsigned int ui; h16x2 h2; } cu, cv;
            cu.ui = u[m]; cv.ui = v[m];
            const h16x2 h = __builtin_elementwise_max(cu.h2 + cv.h2, zero2);
            acc2 = acc2 + h * w2h[m];
        }
        float acc = (float)acc2[0] + (float)acc2[1];
        #pragma unroll
        for (int msk = 1; msk <= 8; msk <<= 1) acc += __shfl_xor(acc, msk);
        if (cl == 0) out[e] = 1.f / (1.f + __expf(-(acc + bb2)));

        if (en >= E) break;
        e = en; u = un; v = vn;
        en = e2; sn = s2; dn = d2;
    }
}

// ===================== last-resort fp32 fallback ==========================

__global__ __launch_bounds__(256, 2) void edge_decoder_fp32_kernel(
    const float* __restrict__ z, const int* __restrict__ eli, const int E,
    const float* __restrict__ w1, const float* __restrict__ b1,
    const float* __restrict__ w2, const float* __restrict__ b2,
    float* __restrict__ out)
{
    __shared__ float sZ[32][256];
    __shared__ float sW[2][32][128];
    const int t = threadIdx.x, wave = t >> 6, lane = t & 63;
    const int e0 = blockIdx.x * 32;
    #pragma unroll
    for (int q = 0; q < 8; ++q) {
        const int e = wave * 8 + q;
        int ge = e0 + e; if (ge >= E) ge = E - 1;
        const int node = (lane < 32) ? eli[ge] : eli[E + ge];
        gload16(z + (size_t)node * HD + (size_t)(lane & 31) * 4, &sZ[e][0]);
    }
    #pragma unroll
    for (int q = 0; q < 4; ++q) {
        const int inst = wave * 4 + q;
        gload16(w1 + inst * 256 + lane * 4, &sW[0][0][0] + inst * 256);
    }
    __syncthreads();
    const int cg = t & 31, eg = t >> 5, c0 = cg * 4;
    float acc[4][4] = {{0.f,0.f,0.f,0.f}};
    for (int kc = 0; kc < 8; ++kc) {
        const int buf = kc & 1;
        if (kc + 1 < 8) {
            const float* gw = w1 + (size_t)(kc + 1) * 32 * HD;
            #pragma unroll
            for (int q = 0; q < 4; ++q) {
                const int inst = wave * 4 + q;
                gload16(gw + inst * 256 + lane * 4, &sW[buf ^ 1][0][0] + inst * 256);
            }
        }
        #pragma unroll
        for (int k4 = 0; k4 < 8; ++k4) {
            float zr[4][4];
            #pragma unroll
            for (int i = 0; i < 4; ++i)
                *(float4*)(&zr[i][0]) = *(const float4*)(&sZ[eg*4+i][kc*32 + k4*4]);
            #pragma unroll
            for (int kk = 0; kk < 4; ++kk) {
                const float4 wv = *(const float4*)(&sW[buf][k4*4+kk][c0]);
                #pragma unroll
                for (int i = 0; i < 4; ++i) {
                    acc[i][0] = fmaf(zr[i][kk], wv.x, acc[i][0]);
                    acc[i][1] = fmaf(zr[i][kk], wv.y, acc[i][1]);
                    acc[i][2] = fmaf(zr[i][kk], wv.z, acc[i][2]);
                    acc[i][3] = fmaf(zr[i][kk], wv.w, acc[i][3]);
                }
            }
        }
        __syncthreads();
    }
    const float4 b1v = *(const float4*)(&b1[c0]);
    const float4 w2v = *(const float4*)(&w2[c0]);
    const float bb2 = b2[0];
    float part[4];
    #pragma unroll
    for (int i = 0; i < 4; ++i)
        part[i] = fmaxf(acc[i][0]+b1v.x,0.f)*w2v.x + fmaxf(acc[i][1]+b1v.y,0.f)*w2v.y
                + fmaxf(acc[i][2]+b1v.z,0.f)*w2v.z + fmaxf(acc[i][3]+b1v.w,0.f)*w2v.w;
    #pragma unroll
    for (int m = 16; m >= 1; m >>= 1)
        #pragma unroll
        for (int i = 0; i < 4; ++i) part[i] += __shfl_xor(part[i], m, 32);
    if (cg == 0) {
        #pragma unroll
        for (int i = 0; i < 4; ++i) {
            const int ge = e0 + eg * 4 + i;
            if (ge < E) out[ge] = 1.0f / (1.0f + __expf(-(part[i] + bb2)));
        }
    }
}

extern "C" void kernel_launch(void* const* d_in, const int* in_sizes, int n_in,
                              void* d_out, int out_size, void* d_ws, size_t ws_size,
                              hipStream_t stream) {
    const float* z  = (const float*)d_in[0];
    const int* eli  = (const int*)d_in[1];
    const float* w1 = (const float*)d_in[2];
    const float* b1 = (const float*)d_in[3];
    const float* w2 = (const float*)d_in[4];
    const float* b2 = (const float*)d_in[5];
    float* out = (float*)d_out;

    const int E  = in_sizes[1] / 2;
    const int NN = in_sizes[0] / HD;
    const int NB = (NN + 255) >> 8;

    size_t off = 0;
    auto take = [&](size_t n) { size_t r = off; off = (off + n + 15) & ~(size_t)15; return r; };
    const size_t o_uv    = take((size_t)NN * KD * 2);
    const size_t o_bp    = take(65536);
    const size_t need_uv = off;
    const size_t o_hist  = take(NBMAX * 4);
    const size_t o_start = take((NBMAX + 1) * 4);
    const size_t o_cur   = take(NBMAX * 4);
    const size_t o_sort  = take((size_t)E * 12);
    const size_t need_sorted = off;

    if (ws_size >= need_sorted && NB <= NBMAX) {
        _Float16* UV = (_Float16*)((char*)d_ws + o_uv);
        unsigned short* Bp = (unsigned short*)((char*)d_ws + o_bp);
        int* hist   = (int*)((char*)d_ws + o_hist);
        int* start  = (int*)((char*)d_ws + o_start);
        int* cursor = (int*)((char*)d_ws + o_cur);
        int* sorted = (int*)((char*)d_ws + o_sort);

        hipMemsetAsync(hist, 0, NBMAX * 4, stream);
        pack_B_kernel<<<16, 256, 0, stream>>>(w1, Bp);
        hist_kernel<<<256, 256, 0, stream>>>(eli, E, NB, hist);
        scan_kernel<<<1, NBMAX, 0, stream>>>(hist, NB, start, cursor);
        scatter_kernel<<<256, 256, 0, stream>>>(eli, E, NB, cursor, sorted);
        uv_gemm_kernel<<<(NN + 127) / 128, 256, 0, stream>>>(z, Bp, b1, UV, NN);
        edge_sorted_kernel<<<2048, 256, 0, stream>>>(UV, sorted, start, NB, w2, b2, out);
    } else if (ws_size >= need_uv) {
        _Float16* UV = (_Float16*)((char*)d_ws + o_uv);
        unsigned short* Bp = (unsigned short*)((char*)d_ws + o_bp);
        pack_B_kernel<<<16, 256, 0, stream>>>(w1, Bp);
        uv_gemm_kernel<<<(NN + 127) / 128, 256, 0, stream>>>(z, Bp, b1, UV, NN);
        edge_uv_f16_kernel<<<2048, 256, 0, stream>>>(UV, eli, E, w2, b2, out);
    } else {
        edge_decoder_fp32_kernel<<<(E + 31) / 32, 256, 0, stream>>>(
            z, eli, E, w1, b1, w2, b2, out);
    }
}

// Round 8
// 103.499 us; speedup vs baseline: 1.0643x; 1.0643x over previous
//
#include <hip/hip_runtime.h>
#include <cstdint>
#include <cstddef>

#define HD 128
#define KD 256
#define NBMAX 512

typedef __attribute__((ext_vector_type(8))) short bf16x8;
typedef __attribute__((ext_vector_type(4))) float f32x4;
typedef __attribute__((ext_vector_type(4))) unsigned int u32x4;
typedef __attribute__((ext_vector_type(2))) _Float16 h16x2;
typedef __attribute__((ext_vector_type(4))) _Float16 h16x4;

typedef const __attribute__((address_space(1))) void gv_t;
typedef __attribute__((address_space(3))) void lv_t;

__device__ __forceinline__ void gload16(const void* g, void* l) {
    __builtin_amdgcn_global_load_lds((gv_t*)g, (lv_t*)l, 16, 0, 0);
}

__device__ __forceinline__ unsigned short f2bf(float x) {   // RNE f32->bf16
    unsigned u = __float_as_uint(x);
    u = (u + 0x7fffu + ((u >> 16) & 1u)) >> 16;
    return (unsigned short)u;
}

// ================= per-node precompute (U' = zW1a+b1, V = zW1b) ============

// pack B + (block 0) zero the sort histogram — same-stream ordering makes
// this a free replacement for the 40us hipMemsetAsync dispatch.
__global__ void pack_B_kernel(const float* __restrict__ w1,
                              unsigned short* __restrict__ Bp,
                              int* __restrict__ hist) {
    if (blockIdx.x == 0 && hist) {
        hist[threadIdx.x] = 0;
        hist[threadIdx.x + 256] = 0;
    }
    const int tid = blockIdx.x * 256 + threadIdx.x;   // 0..4095
    const int lane = tid & 63, nf = (tid >> 6) & 15, kt = tid >> 10;
    const int col = nf * 16 + (lane & 15);
    const int k0 = kt * 32 + (lane >> 4) * 8;
    #pragma unroll
    for (int j = 0; j < 8; ++j) {
        const int k = k0 + j;
        const float v = (col < HD) ? w1[(size_t)k * HD + col]
                                   : w1[(size_t)(HD + k) * HD + (col - HD)];
        Bp[(size_t)tid * 8 + j] = f2bf(v);
    }
}

// UV[n][c] f16. 64-row tiles, swapped-operand MFMA (D^T): lane owns one node,
// 4 consecutive cols per fragment -> h16x4 stores.
__global__ __launch_bounds__(256, 3) void uv_gemm_kernel(
    const float* __restrict__ z, const unsigned short* __restrict__ Bp,
    const float* __restrict__ b1, _Float16* __restrict__ UV, const int NN)
{
    __shared__ __attribute__((aligned(16))) unsigned short sA[64 * HD]; // 16 KB
    char* sAb = (char*)sA;
    const int t = threadIdx.x, wave = t >> 6, l = t & 63;
    const int n0 = blockIdx.x * 64;
    {
        const int r = t >> 2, q4 = t & 3;        // 4 threads per row
        int n = n0 + r; if (n >= NN) n = NN - 1;
        const float* zr = z + (size_t)n * HD + q4 * 32;
        #pragma unroll
        for (int q = 0; q < 8; ++q) {
            const float4 v = *(const float4*)(zr + q * 4);
            ushort4 o;
            o.x = f2bf(v.x); o.y = f2bf(v.y); o.z = f2bf(v.z); o.w = f2bf(v.w);
            const int byte = r * 256 + (q4 * 32 + q * 4) * 2;
            *(ushort4*)(sAb + (byte ^ ((r & 15) << 4))) = o;
        }
    }
    __syncthreads();

    const int waveM = wave >> 1, waveN = wave & 1;   // rows 32*waveM, col half
    f32x4 acc[2][8];
    #pragma unroll
    for (int nf = 0; nf < 8; ++nf) {
        float4 bv = make_float4(0.f, 0.f, 0.f, 0.f);
        if (waveN == 0) bv = *(const float4*)(b1 + nf * 16 + (l >> 4) * 4);
        #pragma unroll
        for (int mf = 0; mf < 2; ++mf) {
            acc[mf][nf][0] = bv.x; acc[mf][nf][1] = bv.y;
            acc[mf][nf][2] = bv.z; acc[mf][nf][3] = bv.w;
        }
    }
    #pragma unroll
    for (int kt = 0; kt < 4; ++kt) {
        bf16x8 bfr[8], af[2];
        #pragma unroll
        for (int nf = 0; nf < 8; ++nf)
            bfr[nf] = *(const bf16x8*)(Bp + (size_t)((kt * 16 + waveN * 8 + nf) * 64 + l) * 8);
        #pragma unroll
        for (int mf = 0; mf < 2; ++mf) {
            const int rr = waveM * 32 + mf * 16 + (l & 15);
            const int byte = rr * 256 + kt * 64 + (l >> 4) * 16;
            af[mf] = *(const bf16x8*)(sAb + (byte ^ ((rr & 15) << 4)));
        }
        #pragma unroll
        for (int mf = 0; mf < 2; ++mf)
            #pragma unroll
            for (int nf = 0; nf < 8; ++nf)
                acc[mf][nf] = __builtin_amdgcn_mfma_f32_16x16x32_bf16(
                    bfr[nf], af[mf], acc[mf][nf], 0, 0, 0);   // swapped: D^T
    }
    #pragma unroll
    for (int mf = 0; mf < 2; ++mf) {
        const int n2 = n0 + waveM * 32 + mf * 16 + (l & 15);
        if (n2 < NN) {
            #pragma unroll
            for (int nf = 0; nf < 8; ++nf) {
                const int c0 = waveN * 128 + nf * 16 + (l >> 4) * 4;
                h16x4 o = (h16x4){(_Float16)acc[mf][nf][0], (_Float16)acc[mf][nf][1],
                                  (_Float16)acc[mf][nf][2], (_Float16)acc[mf][nf][3]};
                *(h16x4*)(UV + (size_t)n2 * KD + c0) = o;
            }
        }
    }
}

// ===================== src-bucket counting sort ==========================

__global__ void hist_kernel(const int* __restrict__ eli, const int E,
                            const int nb, int* __restrict__ hist) {
    __shared__ int lh[NBMAX];
    const int t = threadIdx.x;
    for (int b = t; b < nb; b += 256) lh[b] = 0;
    __syncthreads();
    const int per = (E + gridDim.x - 1) / gridDim.x;
    const int e0 = blockIdx.x * per;
    int e1 = e0 + per; if (e1 > E) e1 = E;
    for (int e = e0 + t; e < e1; e += 256)
        atomicAdd(&lh[eli[e] >> 8], 1);
    __syncthreads();
    for (int b = t; b < nb; b += 256)
        if (lh[b]) atomicAdd(&hist[b], lh[b]);
}

__global__ void scan_kernel(const int* __restrict__ hist, const int nb,
                            int* __restrict__ start, int* __restrict__ cursor) {
    __shared__ int sc[NBMAX];
    const int t = threadIdx.x;            // launched with NBMAX threads
    const int own = (t < nb) ? hist[t] : 0;
    sc[t] = own;
    __syncthreads();
    for (int off = 1; off < NBMAX; off <<= 1) {
        const int v = (t >= off) ? sc[t - off] : 0;
        __syncthreads();
        sc[t] += v;
        __syncthreads();
    }
    if (t < nb) {
        const int ex = sc[t] - own;       // exclusive
        start[t] = ex; cursor[t] = ex;
    }
    if (t == nb - 1) start[nb] = sc[t];
}

__global__ void scatter_kernel(const int* __restrict__ eli, const int E,
                               const int nb, int* __restrict__ cursor,
                               int* __restrict__ sorted) {
    __shared__ int lh[NBMAX];
    __shared__ int lb[NBMAX];
    const int t = threadIdx.x;
    for (int b = t; b < nb; b += 256) lh[b] = 0;
    __syncthreads();
    const int per = (E + gridDim.x - 1) / gridDim.x;
    const int e0 = blockIdx.x * per;
    int e1 = e0 + per; if (e1 > E) e1 = E;
    for (int e = e0 + t; e < e1; e += 256)
        atomicAdd(&lh[eli[e] >> 8], 1);
    __syncthreads();
    for (int b = t; b < nb; b += 256) {
        const int c = lh[b];
        lb[b] = c ? atomicAdd(&cursor[b], c) : 0;
        lh[b] = 0;
    }
    __syncthreads();
    for (int e = e0 + t; e < e1; e += 256) {
        const int s = eli[e];
        const int r = atomicAdd(&lh[s >> 8], 1);
        int* p = sorted + (size_t)(lb[s >> 8] + r) * 3;
        p[0] = s; p[1] = eli[E + e]; p[2] = e;
    }
}

// ============== XCD-pinned sorted edge pass (16 lanes/edge) ===============

__global__ __launch_bounds__(256, 8) void edge_sorted_kernel(
    const _Float16* __restrict__ UV, const int* __restrict__ sorted,
    const int* __restrict__ start, const int NB,
    const float* __restrict__ w2, const float* __restrict__ b2,
    float* __restrict__ out)
{
    const int t = threadIdx.x, cl = t & 15, g = t >> 4;
    const int xcd = blockIdx.x & 7, rank = blockIdx.x >> 3;
    const int nbx = gridDim.x >> 3;
    const int bpx = (NB + 7) >> 3;
    const int blo = xcd * bpx;
    if (blo >= NB) return;
    int bhi = blo + bpx; if (bhi > NB) bhi = NB;
    const int elo = start[blo], ehi = start[bhi];

    h16x2 w2h[4];
    {
        const float4 wlo = *(const float4*)(w2 + cl * 8);
        const float4 whi = *(const float4*)(w2 + cl * 8 + 4);
        w2h[0] = (h16x2){(_Float16)wlo.x, (_Float16)wlo.y};
        w2h[1] = (h16x2){(_Float16)wlo.z, (_Float16)wlo.w};
        w2h[2] = (h16x2){(_Float16)whi.x, (_Float16)whi.y};
        w2h[3] = (h16x2){(_Float16)whi.z, (_Float16)whi.w};
    }
    const float bb2 = b2[0];
    const h16x2 zero2 = (h16x2){(_Float16)0.f, (_Float16)0.f};

    const int stride = nbx * 16;
    int i = elo + rank * 16 + g;
    if (i >= ehi) return;
    const int* tp = sorted + (size_t)i * 3;
    int e = tp[2];
    u32x4 u = *(const u32x4*)(UV + (size_t)tp[0] * KD + cl * 8);
    u32x4 v = *(const u32x4*)(UV + (size_t)tp[1] * KD + HD + cl * 8);

    for (;;) {
        const int i2 = i + stride;
        int e2 = 0; u32x4 un, vn;
        if (i2 < ehi) {
            const int* tq = sorted + (size_t)i2 * 3;
            e2 = tq[2];
            un = *(const u32x4*)(UV + (size_t)tq[0] * KD + cl * 8);
            vn = *(const u32x4*)(UV + (size_t)tq[1] * KD + HD + cl * 8);
        }
        h16x2 acc2 = zero2;
        #pragma unroll
        for (int m = 0; m < 4; ++m) {
            union { unsigned int ui; h16x2 h2; } cu, cv;
            cu.ui = u[m]; cv.ui = v[m];
            const h16x2 h = __builtin_elementwise_max(cu.h2 + cv.h2, zero2);
            acc2 = acc2 + h * w2h[m];
        }
        float acc = (float)acc2[0] + (float)acc2[1];
        #pragma unroll
        for (int msk = 1; msk <= 8; msk <<= 1) acc += __shfl_xor(acc, msk);
        if (cl == 0) out[e] = 1.f / (1.f + __expf(-(acc + bb2)));
        if (i2 >= ehi) break;
        i = i2; e = e2; u = un; v = vn;
    }
}

// ============== mid-tier fallback: unsorted edge pass ====================

__global__ __launch_bounds__(256, 8) void edge_uv_f16_kernel(
    const _Float16* __restrict__ UV, const int* __restrict__ eli,
    const int E, const float* __restrict__ w2, const float* __restrict__ b2,
    float* __restrict__ out)
{
    const int t = threadIdx.x;
    const int cl = t & 15;
    const int gid = (blockIdx.x * 256 + t) >> 4;
    const int ng = (gridDim.x * 256) >> 4;

    h16x2 w2h[4];
    {
        const float4 wlo = *(const float4*)(w2 + cl * 8);
        const float4 whi = *(const float4*)(w2 + cl * 8 + 4);
        w2h[0] = (h16x2){(_Float16)wlo.x, (_Float16)wlo.y};
        w2h[1] = (h16x2){(_Float16)wlo.z, (_Float16)wlo.w};
        w2h[2] = (h16x2){(_Float16)whi.x, (_Float16)whi.y};
        w2h[3] = (h16x2){(_Float16)whi.z, (_Float16)whi.w};
    }
    const float bb2 = b2[0];
    const h16x2 zero2 = (h16x2){(_Float16)0.f, (_Float16)0.f};

    int e = gid;
    if (e >= E) return;
    int s = eli[e], d = eli[E + e];
    u32x4 u = *(const u32x4*)(UV + (size_t)s * KD + cl * 8);
    u32x4 v = *(const u32x4*)(UV + (size_t)d * KD + HD + cl * 8);
    int en = e + ng;
    int enc = (en < E) ? en : (E - 1);
    int sn = eli[enc], dn = eli[E + enc];

    for (;;) {
        const int e2 = en + ng;
        const int e2c = (e2 < E) ? e2 : (E - 1);
        const int s2 = eli[e2c], d2 = eli[E + e2c];
        const u32x4 un = *(const u32x4*)(UV + (size_t)sn * KD + cl * 8);
        const u32x4 vn = *(const u32x4*)(UV + (size_t)dn * KD + HD + cl * 8);

        h16x2 acc2 = zero2;
        #pragma unroll
        for (int m = 0; m < 4; ++m) {
            union { unsigned int ui; h16x2 h2; } cu, cv;
            cu.ui = u[m]; cv.ui = v[m];
            const h16x2 h = __builtin_elementwise_max(cu.h2 + cv.h2, zero2);
            acc2 = acc2 + h * w2h[m];
        }
        float acc = (float)acc2[0] + (float)acc2[1];
        #pragma unroll
        for (int msk = 1; msk <= 8; msk <<= 1) acc += __shfl_xor(acc, msk);
        if (cl == 0) out[e] = 1.f / (1.f + __expf(-(acc + bb2)));

        if (en >= E) break;
        e = en; u = un; v = vn;
        en = e2; sn = s2; dn = d2;
    }
}

// ===================== last-resort fp32 fallback ==========================

__global__ __launch_bounds__(256, 2) void edge_decoder_fp32_kernel(
    const float* __restrict__ z, const int* __restrict__ eli, const int E,
    const float* __restrict__ w1, const float* __restrict__ b1,
    const float* __restrict__ w2, const float* __restrict__ b2,
    float* __restrict__ out)
{
    __shared__ float sZ[32][256];
    __shared__ float sW[2][32][128];
    const int t = threadIdx.x, wave = t >> 6, lane = t & 63;
    const int e0 = blockIdx.x * 32;
    #pragma unroll
    for (int q = 0; q < 8; ++q) {
        const int e = wave * 8 + q;
        int ge = e0 + e; if (ge >= E) ge = E - 1;
        const int node = (lane < 32) ? eli[ge] : eli[E + ge];
        gload16(z + (size_t)node * HD + (size_t)(lane & 31) * 4, &sZ[e][0]);
    }
    #pragma unroll
    for (int q = 0; q < 4; ++q) {
        const int inst = wave * 4 + q;
        gload16(w1 + inst * 256 + lane * 4, &sW[0][0][0] + inst * 256);
    }
    __syncthreads();
    const int cg = t & 31, eg = t >> 5, c0 = cg * 4;
    float acc[4][4] = {{0.f,0.f,0.f,0.f}};
    for (int kc = 0; kc < 8; ++kc) {
        const int buf = kc & 1;
        if (kc + 1 < 8) {
            const float* gw = w1 + (size_t)(kc + 1) * 32 * HD;
            #pragma unroll
            for (int q = 0; q < 4; ++q) {
                const int inst = wave * 4 + q;
                gload16(gw + inst * 256 + lane * 4, &sW[buf ^ 1][0][0] + inst * 256);
            }
        }
        #pragma unroll
        for (int k4 = 0; k4 < 8; ++k4) {
            float zr[4][4];
            #pragma unroll
            for (int i = 0; i < 4; ++i)
                *(float4*)(&zr[i][0]) = *(const float4*)(&sZ[eg*4+i][kc*32 + k4*4]);
            #pragma unroll
            for (int kk = 0; kk < 4; ++kk) {
                const float4 wv = *(const float4*)(&sW[buf][k4*4+kk][c0]);
                #pragma unroll
                for (int i = 0; i < 4; ++i) {
                    acc[i][0] = fmaf(zr[i][kk], wv.x, acc[i][0]);
                    acc[i][1] = fmaf(zr[i][kk], wv.y, acc[i][1]);
                    acc[i][2] = fmaf(zr[i][kk], wv.z, acc[i][2]);
                    acc[i][3] = fmaf(zr[i][kk], wv.w, acc[i][3]);
                }
            }
        }
        __syncthreads();
    }
    const float4 b1v = *(const float4*)(&b1[c0]);
    const float4 w2v = *(const float4*)(&w2[c0]);
    const float bb2 = b2[0];
    float part[4];
    #pragma unroll
    for (int i = 0; i < 4; ++i)
        part[i] = fmaxf(acc[i][0]+b1v.x,0.f)*w2v.x + fmaxf(acc[i][1]+b1v.y,0.f)*w2v.y
                + fmaxf(acc[i][2]+b1v.z,0.f)*w2v.z + fmaxf(acc[i][3]+b1v.w,0.f)*w2v.w;
    #pragma unroll
    for (int m = 16; m >= 1; m >>= 1)
        #pragma unroll
        for (int i = 0; i < 4; ++i) part[i] += __shfl_xor(part[i], m, 32);
    if (cg == 0) {
        #pragma unroll
        for (int i = 0; i < 4; ++i) {
            const int ge = e0 + eg * 4 + i;
            if (ge < E) out[ge] = 1.0f / (1.0f + __expf(-(part[i] + bb2)));
        }
    }
}

extern "C" void kernel_launch(void* const* d_in, const int* in_sizes, int n_in,
                              void* d_out, int out_size, void* d_ws, size_t ws_size,
                              hipStream_t stream) {
    const float* z  = (const float*)d_in[0];
    const int* eli  = (const int*)d_in[1];
    const float* w1 = (const float*)d_in[2];
    const float* b1 = (const float*)d_in[3];
    const float* w2 = (const float*)d_in[4];
    const float* b2 = (const float*)d_in[5];
    float* out = (float*)d_out;

    const int E  = in_sizes[1] / 2;
    const int NN = in_sizes[0] / HD;
    const int NB = (NN + 255) >> 8;

    size_t off = 0;
    auto take = [&](size_t n) { size_t r = off; off = (off + n + 15) & ~(size_t)15; return r; };
    const size_t o_uv    = take((size_t)NN * KD * 2);
    const size_t o_bp    = take(65536);
    const size_t need_uv = off;
    const size_t o_hist  = take(NBMAX * 4);
    const size_t o_start = take((NBMAX + 1) * 4);
    const size_t o_cur   = take(NBMAX * 4);
    const size_t o_sort  = take((size_t)E * 12);
    const size_t need_sorted = off;

    const int uv_grid = (NN + 63) / 64;

    if (ws_size >= need_sorted && NB <= NBMAX) {
        _Float16* UV = (_Float16*)((char*)d_ws + o_uv);
        unsigned short* Bp = (unsigned short*)((char*)d_ws + o_bp);
        int* hist   = (int*)((char*)d_ws + o_hist);
        int* start  = (int*)((char*)d_ws + o_start);
        int* cursor = (int*)((char*)d_ws + o_cur);
        int* sorted = (int*)((char*)d_ws + o_sort);

        pack_B_kernel<<<16, 256, 0, stream>>>(w1, Bp, hist);
        hist_kernel<<<256, 256, 0, stream>>>(eli, E, NB, hist);
        scan_kernel<<<1, NBMAX, 0, stream>>>(hist, NB, start, cursor);
        scatter_kernel<<<256, 256, 0, stream>>>(eli, E, NB, cursor, sorted);
        uv_gemm_kernel<<<uv_grid, 256, 0, stream>>>(z, Bp, b1, UV, NN);
        edge_sorted_kernel<<<2048, 256, 0, stream>>>(UV, sorted, start, NB, w2, b2, out);
    } else if (ws_size >= need_uv) {
        _Float16* UV = (_Float16*)((char*)d_ws + o_uv);
        unsigned short* Bp = (unsigned short*)((char*)d_ws + o_bp);
        pack_B_kernel<<<16, 256, 0, stream>>>(w1, Bp, (int*)nullptr);
        uv_gemm_kernel<<<uv_grid, 256, 0, stream>>>(z, Bp, b1, UV, NN);
        edge_uv_f16_kernel<<<2048, 256, 0, stream>>>(UV, eli, E, w2, b2, out);
    } else {
        edge_decoder_fp32_kernel<<<(E + 31) / 32, 256, 0, stream>>>(
            z, eli, E, w1, b1, w2, b2, out);
    }
}

// Round 9
// 103.127 us; speedup vs baseline: 1.0682x; 1.0036x over previous
//
#include <hip/hip_runtime.h>
#include <cstdint>
#include <cstddef>

#define HD 128
#define KD 256
#define NBMAX 512
#define HBLK 64

typedef __attribute__((ext_vector_type(8))) short bf16x8;
typedef __attribute__((ext_vector_type(4))) float f32x4;
typedef __attribute__((ext_vector_type(4))) unsigned int u32x4;
typedef __attribute__((ext_vector_type(2))) _Float16 h16x2;
typedef __attribute__((ext_vector_type(4))) _Float16 h16x4;

typedef const __attribute__((address_space(1))) void gv_t;
typedef __attribute__((address_space(3))) void lv_t;

__device__ __forceinline__ void gload16(const void* g, void* l) {
    __builtin_amdgcn_global_load_lds((gv_t*)g, (lv_t*)l, 16, 0, 0);
}

__device__ __forceinline__ unsigned short f2bf(float x) {   // RNE f32->bf16
    unsigned u = __float_as_uint(x);
    u = (u + 0x7fffu + ((u >> 16) & 1u)) >> 16;
    return (unsigned short)u;
}

// ====== fused: pack B (blocks 0..15) + per-block histogram (blocks 16..) ======
// hist partials are plain stores into partial[hb][bucket] — no zero-init, no race.
__global__ void pack_hist_kernel(const float* __restrict__ w1,
                                 unsigned short* __restrict__ Bp,
                                 const int* __restrict__ eli, const int E,
                                 const int nb, int* __restrict__ partial) {
    __shared__ int lh[NBMAX];
    if (blockIdx.x < 16) {
        const int tid = blockIdx.x * 256 + threadIdx.x;   // 0..4095
        const int lane = tid & 63, nf = (tid >> 6) & 15, kt = tid >> 10;
        const int col = nf * 16 + (lane & 15);
        const int k0 = kt * 32 + (lane >> 4) * 8;
        #pragma unroll
        for (int j = 0; j < 8; ++j) {
            const int k = k0 + j;
            const float v = (col < HD) ? w1[(size_t)k * HD + col]
                                       : w1[(size_t)(HD + k) * HD + (col - HD)];
            Bp[(size_t)tid * 8 + j] = f2bf(v);
        }
        return;
    }
    if (!partial) return;
    const int hb = blockIdx.x - 16;
    const int t = threadIdx.x;
    for (int b = t; b < nb; b += 256) lh[b] = 0;
    __syncthreads();
    const int per = (E + HBLK - 1) / HBLK;
    const int e0 = hb * per;
    int e1 = e0 + per; if (e1 > E) e1 = E;
    for (int e = e0 + t; e < e1; e += 256)
        atomicAdd(&lh[eli[e] >> 8], 1);
    __syncthreads();
    for (int b = t; b < nb; b += 256)
        partial[hb * NBMAX + b] = lh[b];
}

// scan: sum 64 partials per bucket, then inclusive scan -> start/cursor
__global__ void scan_kernel(const int* __restrict__ partial, const int nb,
                            int* __restrict__ start, int* __restrict__ cursor) {
    __shared__ int sc[NBMAX];
    const int t = threadIdx.x;            // NBMAX threads
    int own = 0;
    if (t < nb)
        for (int h = 0; h < HBLK; ++h) own += partial[h * NBMAX + t];
    sc[t] = own;
    __syncthreads();
    for (int off = 1; off < NBMAX; off <<= 1) {
        const int v = (t >= off) ? sc[t - off] : 0;
        __syncthreads();
        sc[t] += v;
        __syncthreads();
    }
    if (t < nb) {
        const int ex = sc[t] - own;       // exclusive
        start[t] = ex; cursor[t] = ex;
    }
    if (t == nb - 1) start[nb] = sc[t];
}

__global__ void scatter_kernel(const int* __restrict__ eli, const int E,
                               const int nb, int* __restrict__ cursor,
                               int* __restrict__ sorted) {
    __shared__ int lh[NBMAX];
    __shared__ int lb[NBMAX];
    const int t = threadIdx.x;
    for (int b = t; b < nb; b += 256) lh[b] = 0;
    __syncthreads();
    const int per = (E + gridDim.x - 1) / gridDim.x;
    const int e0 = blockIdx.x * per;
    int e1 = e0 + per; if (e1 > E) e1 = E;
    for (int e = e0 + t; e < e1; e += 256)
        atomicAdd(&lh[eli[e] >> 8], 1);
    __syncthreads();
    for (int b = t; b < nb; b += 256) {
        const int c = lh[b];
        lb[b] = c ? atomicAdd(&cursor[b], c) : 0;
        lh[b] = 0;
    }
    __syncthreads();
    for (int e = e0 + t; e < e1; e += 256) {
        const int s = eli[e];
        const int r = atomicAdd(&lh[s >> 8], 1);
        int* p = sorted + (size_t)(lb[s >> 8] + r) * 3;
        p[0] = s; p[1] = eli[E + e]; p[2] = e;
    }
}

// ========== uv_gemm: Bp staged to LDS (latency fix), 64-row tiles ==========
// UV[n][c] f16: c<128 -> U' = z@W1a + b1 ; c>=128 -> V = z@W1b.
// Swapped-operand MFMA (D^T): lane owns one node, 4 consecutive cols/frag.
__global__ __launch_bounds__(256, 2) void uv_gemm_kernel(
    const float* __restrict__ z, const unsigned short* __restrict__ Bp,
    const float* __restrict__ b1, _Float16* __restrict__ UV, const int NN)
{
    __shared__ __attribute__((aligned(16))) unsigned short sA[64 * HD];   // 16 KB
    __shared__ __attribute__((aligned(16))) unsigned short sB[32 * 1024]; // 64 KB
    char* sAb = (char*)sA;
    const char* sBb = (const char*)sB;
    const int t = threadIdx.x, wave = t >> 6, l = t & 63;
    const int n0 = blockIdx.x * 64;

    // issue Bp -> LDS first (64 x 1KB insts, 16/wave); overlaps z staging
    #pragma unroll
    for (int q = 0; q < 16; ++q) {
        const int i = wave * 16 + q;
        gload16((const char*)Bp + i * 1024 + l * 16, (char*)sB + i * 1024);
    }
    // z tile f32 -> bf16 -> LDS (swizzled)
    {
        const int r = t >> 2, q4 = t & 3;        // 4 threads per row
        int n = n0 + r; if (n >= NN) n = NN - 1;
        const float* zr = z + (size_t)n * HD + q4 * 32;
        #pragma unroll
        for (int q = 0; q < 8; ++q) {
            const float4 v = *(const float4*)(zr + q * 4);
            ushort4 o;
            o.x = f2bf(v.x); o.y = f2bf(v.y); o.z = f2bf(v.z); o.w = f2bf(v.w);
            const int byte = r * 256 + (q4 * 32 + q * 4) * 2;
            *(ushort4*)(sAb + (byte ^ ((r & 15) << 4))) = o;
        }
    }
    __syncthreads();

    const int waveM = wave >> 1, waveN = wave & 1;   // rows 32*waveM, col half
    f32x4 acc[2][8];
    #pragma unroll
    for (int nf = 0; nf < 8; ++nf) {
        float4 bv = make_float4(0.f, 0.f, 0.f, 0.f);
        if (waveN == 0) bv = *(const float4*)(b1 + nf * 16 + (l >> 4) * 4);
        #pragma unroll
        for (int mf = 0; mf < 2; ++mf) {
            acc[mf][nf][0] = bv.x; acc[mf][nf][1] = bv.y;
            acc[mf][nf][2] = bv.z; acc[mf][nf][3] = bv.w;
        }
    }
    #pragma unroll
    for (int kt = 0; kt < 4; ++kt) {
        bf16x8 bfr[8], af[2];
        #pragma unroll
        for (int nf = 0; nf < 8; ++nf)
            bfr[nf] = *(const bf16x8*)(sBb + (size_t)((kt * 16 + waveN * 8 + nf) * 64 + l) * 16);
        #pragma unroll
        for (int mf = 0; mf < 2; ++mf) {
            const int rr = waveM * 32 + mf * 16 + (l & 15);
            const int byte = rr * 256 + kt * 64 + (l >> 4) * 16;
            af[mf] = *(const bf16x8*)(sAb + (byte ^ ((rr & 15) << 4)));
        }
        #pragma unroll
        for (int mf = 0; mf < 2; ++mf)
            #pragma unroll
            for (int nf = 0; nf < 8; ++nf)
                acc[mf][nf] = __builtin_amdgcn_mfma_f32_16x16x32_bf16(
                    bfr[nf], af[mf], acc[mf][nf], 0, 0, 0);   // swapped: D^T
    }
    #pragma unroll
    for (int mf = 0; mf < 2; ++mf) {
        const int n2 = n0 + waveM * 32 + mf * 16 + (l & 15);
        if (n2 < NN) {
            #pragma unroll
            for (int nf = 0; nf < 8; ++nf) {
                const int c0 = waveN * 128 + nf * 16 + (l >> 4) * 4;
                h16x4 o = (h16x4){(_Float16)acc[mf][nf][0], (_Float16)acc[mf][nf][1],
                                  (_Float16)acc[mf][nf][2], (_Float16)acc[mf][nf][3]};
                *(h16x4*)(UV + (size_t)n2 * KD + c0) = o;
            }
        }
    }
}

// ============== XCD-pinned sorted edge pass (16 lanes/edge) ===============

__global__ __launch_bounds__(256, 8) void edge_sorted_kernel(
    const _Float16* __restrict__ UV, const int* __restrict__ sorted,
    const int* __restrict__ start, const int NB,
    const float* __restrict__ w2, const float* __restrict__ b2,
    float* __restrict__ out)
{
    const int t = threadIdx.x, cl = t & 15, g = t >> 4;
    const int xcd = blockIdx.x & 7, rank = blockIdx.x >> 3;
    const int nbx = gridDim.x >> 3;
    const int bpx = (NB + 7) >> 3;
    const int blo = xcd * bpx;
    if (blo >= NB) return;
    int bhi = blo + bpx; if (bhi > NB) bhi = NB;
    const int elo = start[blo], ehi = start[bhi];

    h16x2 w2h[4];
    {
        const float4 wlo = *(const float4*)(w2 + cl * 8);
        const float4 whi = *(const float4*)(w2 + cl * 8 + 4);
        w2h[0] = (h16x2){(_Float16)wlo.x, (_Float16)wlo.y};
        w2h[1] = (h16x2){(_Float16)wlo.z, (_Float16)wlo.w};
        w2h[2] = (h16x2){(_Float16)whi.x, (_Float16)whi.y};
        w2h[3] = (h16x2){(_Float16)whi.z, (_Float16)whi.w};
    }
    const float bb2 = b2[0];
    const h16x2 zero2 = (h16x2){(_Float16)0.f, (_Float16)0.f};

    const int stride = nbx * 16;
    int i = elo + rank * 16 + g;
    if (i >= ehi) return;
    const int* tp = sorted + (size_t)i * 3;
    int e = tp[2];
    u32x4 u = *(const u32x4*)(UV + (size_t)tp[0] * KD + cl * 8);
    u32x4 v = *(const u32x4*)(UV + (size_t)tp[1] * KD + HD + cl * 8);

    for (;;) {
        const int i2 = i + stride;
        int e2 = 0; u32x4 un, vn;
        if (i2 < ehi) {
            const int* tq = sorted + (size_t)i2 * 3;
            e2 = tq[2];
            un = *(const u32x4*)(UV + (size_t)tq[0] * KD + cl * 8);
            vn = *(const u32x4*)(UV + (size_t)tq[1] * KD + HD + cl * 8);
        }
        h16x2 acc2 = zero2;
        #pragma unroll
        for (int m = 0; m < 4; ++m) {
            union { unsigned int ui; h16x2 h2; } cu, cv;
            cu.ui = u[m]; cv.ui = v[m];
            const h16x2 h = __builtin_elementwise_max(cu.h2 + cv.h2, zero2);
            acc2 = acc2 + h * w2h[m];
        }
        float acc = (float)acc2[0] + (float)acc2[1];
        #pragma unroll
        for (int msk = 1; msk <= 8; msk <<= 1) acc += __shfl_xor(acc, msk);
        if (cl == 0) out[e] = 1.f / (1.f + __expf(-(acc + bb2)));
        if (i2 >= ehi) break;
        i = i2; e = e2; u = un; v = vn;
    }
}

// ============== mid-tier fallback: unsorted edge pass ====================

__global__ __launch_bounds__(256, 8) void edge_uv_f16_kernel(
    const _Float16* __restrict__ UV, const int* __restrict__ eli,
    const int E, const float* __restrict__ w2, const float* __restrict__ b2,
    float* __restrict__ out)
{
    const int t = threadIdx.x;
    const int cl = t & 15;
    const int gid = (blockIdx.x * 256 + t) >> 4;
    const int ng = (gridDim.x * 256) >> 4;

    h16x2 w2h[4];
    {
        const float4 wlo = *(const float4*)(w2 + cl * 8);
        const float4 whi = *(const float4*)(w2 + cl * 8 + 4);
        w2h[0] = (h16x2){(_Float16)wlo.x, (_Float16)wlo.y};
        w2h[1] = (h16x2){(_Float16)wlo.z, (_Float16)wlo.w};
        w2h[2] = (h16x2){(_Float16)whi.x, (_Float16)whi.y};
        w2h[3] = (h16x2){(_Float16)whi.z, (_Float16)whi.w};
    }
    const float bb2 = b2[0];
    const h16x2 zero2 = (h16x2){(_Float16)0.f, (_Float16)0.f};

    int e = gid;
    if (e >= E) return;
    int s = eli[e], d = eli[E + e];
    u32x4 u = *(const u32x4*)(UV + (size_t)s * KD + cl * 8);
    u32x4 v = *(const u32x4*)(UV + (size_t)d * KD + HD + cl * 8);
    int en = e + ng;
    int enc = (en < E) ? en : (E - 1);
    int sn = eli[enc], dn = eli[E + enc];

    for (;;) {
        const int e2 = en + ng;
        const int e2c = (e2 < E) ? e2 : (E - 1);
        const int s2 = eli[e2c], d2 = eli[E + e2c];
        const u32x4 un = *(const u32x4*)(UV + (size_t)sn * KD + cl * 8);
        const u32x4 vn = *(const u32x4*)(UV + (size_t)dn * KD + HD + cl * 8);

        h16x2 acc2 = zero2;
        #pragma unroll
        for (int m = 0; m < 4; ++m) {
            union { unsigned int ui; h16x2 h2; } cu, cv;
            cu.ui = u[m]; cv.ui = v[m];
            const h16x2 h = __builtin_elementwise_max(cu.h2 + cv.h2, zero2);
            acc2 = acc2 + h * w2h[m];
        }
        float acc = (float)acc2[0] + (float)acc2[1];
        #pragma unroll
        for (int msk = 1; msk <= 8; msk <<= 1) acc += __shfl_xor(acc, msk);
        if (cl == 0) out[e] = 1.f / (1.f + __expf(-(acc + bb2)));

        if (en >= E) break;
        e = en; u = un; v = vn;
        en = e2; sn = s2; dn = d2;
    }
}

// ===================== last-resort fp32 fallback ==========================

__global__ __launch_bounds__(256, 2) void edge_decoder_fp32_kernel(
    const float* __restrict__ z, const int* __restrict__ eli, const int E,
    const float* __restrict__ w1, const float* __restrict__ b1,
    const float* __restrict__ w2, const float* __restrict__ b2,
    float* __restrict__ out)
{
    __shared__ float sZ[32][256];
    __shared__ float sW[2][32][128];
    const int t = threadIdx.x, wave = t >> 6, lane = t & 63;
    const int e0 = blockIdx.x * 32;
    #pragma unroll
    for (int q = 0; q < 8; ++q) {
        const int e = wave * 8 + q;
        int ge = e0 + e; if (ge >= E) ge = E - 1;
        const int node = (lane < 32) ? eli[ge] : eli[E + ge];
        gload16(z + (size_t)node * HD + (size_t)(lane & 31) * 4, &sZ[e][0]);
    }
    #pragma unroll
    for (int q = 0; q < 4; ++q) {
        const int inst = wave * 4 + q;
        gload16(w1 + inst * 256 + lane * 4, &sW[0][0][0] + inst * 256);
    }
    __syncthreads();
    const int cg = t & 31, eg = t >> 5, c0 = cg * 4;
    float acc[4][4] = {{0.f,0.f,0.f,0.f}};
    for (int kc = 0; kc < 8; ++kc) {
        const int buf = kc & 1;
        if (kc + 1 < 8) {
            const float* gw = w1 + (size_t)(kc + 1) * 32 * HD;
            #pragma unroll
            for (int q = 0; q < 4; ++q) {
                const int inst = wave * 4 + q;
                gload16(gw + inst * 256 + lane * 4, &sW[buf ^ 1][0][0] + inst * 256);
            }
        }
        #pragma unroll
        for (int k4 = 0; k4 < 8; ++k4) {
            float zr[4][4];
            #pragma unroll
            for (int i = 0; i < 4; ++i)
                *(float4*)(&zr[i][0]) = *(const float4*)(&sZ[eg*4+i][kc*32 + k4*4]);
            #pragma unroll
            for (int kk = 0; kk < 4; ++kk) {
                const float4 wv = *(const float4*)(&sW[buf][k4*4+kk][c0]);
                #pragma unroll
                for (int i = 0; i < 4; ++i) {
                    acc[i][0] = fmaf(zr[i][kk], wv.x, acc[i][0]);
                    acc[i][1] = fmaf(zr[i][kk], wv.y, acc[i][1]);
                    acc[i][2] = fmaf(zr[i][kk], wv.z, acc[i][2]);
                    acc[i][3] = fmaf(zr[i][kk], wv.w, acc[i][3]);
                }
            }
        }
        __syncthreads();
    }
    const float4 b1v = *(const float4*)(&b1[c0]);
    const float4 w2v = *(const float4*)(&w2[c0]);
    const float bb2 = b2[0];
    float part[4];
    #pragma unroll
    for (int i = 0; i < 4; ++i)
        part[i] = fmaxf(acc[i][0]+b1v.x,0.f)*w2v.x + fmaxf(acc[i][1]+b1v.y,0.f)*w2v.y
                + fmaxf(acc[i][2]+b1v.z,0.f)*w2v.z + fmaxf(acc[i][3]+b1v.w,0.f)*w2v.w;
    #pragma unroll
    for (int m = 16; m >= 1; m >>= 1)
        #pragma unroll
        for (int i = 0; i < 4; ++i) part[i] += __shfl_xor(part[i], m, 32);
    if (cg == 0) {
        #pragma unroll
        for (int i = 0; i < 4; ++i) {
            const int ge = e0 + eg * 4 + i;
            if (ge < E) out[ge] = 1.0f / (1.0f + __expf(-(part[i] + bb2)));
        }
    }
}

extern "C" void kernel_launch(void* const* d_in, const int* in_sizes, int n_in,
                              void* d_out, int out_size, void* d_ws, size_t ws_size,
                              hipStream_t stream) {
    const float* z  = (const float*)d_in[0];
    const int* eli  = (const int*)d_in[1];
    const float* w1 = (const float*)d_in[2];
    const float* b1 = (const float*)d_in[3];
    const float* w2 = (const float*)d_in[4];
    const float* b2 = (const float*)d_in[5];
    float* out = (float*)d_out;

    const int E  = in_sizes[1] / 2;
    const int NN = in_sizes[0] / HD;
    const int NB = (NN + 255) >> 8;

    size_t off = 0;
    auto take = [&](size_t n) { size_t r = off; off = (off + n + 15) & ~(size_t)15; return r; };
    const size_t o_uv    = take((size_t)NN * KD * 2);
    const size_t o_bp    = take(65536);
    const size_t need_uv = off;
    const size_t o_part  = take((size_t)HBLK * NBMAX * 4);
    const size_t o_start = take((NBMAX + 1) * 4);
    const size_t o_cur   = take(NBMAX * 4);
    const size_t o_sort  = take((size_t)E * 12);
    const size_t need_sorted = off;

    const int uv_grid = (NN + 63) / 64;

    if (ws_size >= need_sorted && NB <= NBMAX) {
        _Float16* UV = (_Float16*)((char*)d_ws + o_uv);
        unsigned short* Bp = (unsigned short*)((char*)d_ws + o_bp);
        int* partial = (int*)((char*)d_ws + o_part);
        int* start   = (int*)((char*)d_ws + o_start);
        int* cursor  = (int*)((char*)d_ws + o_cur);
        int* sorted  = (int*)((char*)d_ws + o_sort);

        pack_hist_kernel<<<16 + HBLK, 256, 0, stream>>>(w1, Bp, eli, E, NB, partial);
        scan_kernel<<<1, NBMAX, 0, stream>>>(partial, NB, start, cursor);
        scatter_kernel<<<256, 256, 0, stream>>>(eli, E, NB, cursor, sorted);
        uv_gemm_kernel<<<uv_grid, 256, 0, stream>>>(z, Bp, b1, UV, NN);
        edge_sorted_kernel<<<2048, 256, 0, stream>>>(UV, sorted, start, NB, w2, b2, out);
    } else if (ws_size >= need_uv) {
        _Float16* UV = (_Float16*)((char*)d_ws + o_uv);
        unsigned short* Bp = (unsigned short*)((char*)d_ws + o_bp);
        pack_hist_kernel<<<16, 256, 0, stream>>>(w1, Bp, eli, 0, 0, (int*)nullptr);
        uv_gemm_kernel<<<uv_grid, 256, 0, stream>>>(z, Bp, b1, UV, NN);
        edge_uv_f16_kernel<<<2048, 256, 0, stream>>>(UV, eli, E, w2, b2, out);
    } else {
        edge_decoder_fp32_kernel<<<(E + 31) / 32, 256, 0, stream>>>(
            z, eli, E, w1, b1, w2, b2, out);
    }
}